// Round 9
// baseline (400.428 us; speedup 1.0000x reference)
//
#include <hip/hip_runtime.h>
#include <hip/hip_bf16.h>
#include <math.h>

#define D 128
#define SA 144   // LDS row stride (bf16): 72 dwords % 32 = 8 -> conflict-free b128 reads

typedef __attribute__((ext_vector_type(8))) short bf16x8;
typedef __attribute__((ext_vector_type(4))) float f32x4;

static __device__ __forceinline__ short f2b(float f) {
    unsigned u = __builtin_bit_cast(unsigned, f);
    unsigned r = (u + 0x7FFFu + ((u >> 16) & 1u)) >> 16;
    return (short)r;
}
static __device__ __forceinline__ float b2f(short b) {
    unsigned u = ((unsigned)(unsigned short)b) << 16;
    return __builtin_bit_cast(float, u);
}

// ---------------- prep: conv_x + conv_w + bucket histogram, one launch ----------------

struct PrepArgs {
    const float* x; short* xb; int total4; int xb_blocks;
    const float* w[6]; short* wo[6]; int w_blocks;
    const int* dst; int* bcnt; int E;
};

__global__ __launch_bounds__(256) void prep_kernel(PrepArgs a) {
    int bid = blockIdx.x, tid = threadIdx.x;
    if (bid < a.xb_blocks) {
        int idx = bid * 256 + tid;
        if (idx < a.total4) {
            float4 v = ((const float4*)a.x)[idx];
            short4 o;
            o.x = f2b(v.x); o.y = f2b(v.y); o.z = f2b(v.z); o.w = f2b(v.w);
            ((short4*)a.xb)[idx] = o;
        }
        return;
    }
    if (bid < a.xb_blocks + a.w_blocks) {
        int idx4 = (bid - a.xb_blocks) * 256 + tid;
        int base = idx4 * 4;
        int m = base >> 14;
        int i = base & 16383;
        const float* W = a.w[m];
        short* O = a.wo[m];
        int k = i >> 7, nn = i & 127;
        float4 v = *(const float4*)(W + k * D + nn);
        O[(nn + 0) * D + k] = f2b(v.x);
        O[(nn + 1) * D + k] = f2b(v.y);
        O[(nn + 2) * D + k] = f2b(v.z);
        O[(nn + 3) * D + k] = f2b(v.w);
        return;
    }
    __shared__ int hist[512];
    hist[tid] = 0; hist[tid + 256] = 0;
    __syncthreads();
    int e0 = (bid - a.xb_blocks - a.w_blocks) * 4096;
#pragma unroll
    for (int i = 0; i < 16; ++i) {
        int e = e0 + i * 256 + tid;
        if (e < a.E) atomicAdd(&hist[a.dst[e] >> 7], 1);
    }
    __syncthreads();
    int c = hist[tid];       if (c) atomicAdd(&a.bcnt[tid], c);
    c = hist[tid + 256];     if (c) atomicAdd(&a.bcnt[tid + 256], c);
}

// ---------------- scan of 512 bucket counts (one block) ----------------

__global__ __launch_bounds__(256) void scan512_kernel(const int* __restrict__ bcnt,
                                                      int* __restrict__ gbase,
                                                      int* __restrict__ gcursor) {
    __shared__ int sc[256];
    int tid = threadIdx.x;
    int a0 = bcnt[2 * tid], a1 = bcnt[2 * tid + 1];
    int s = a0 + a1;
    sc[tid] = s;
    __syncthreads();
    for (int off = 1; off < 256; off <<= 1) {
        int t = (tid >= off) ? sc[tid - off] : 0;
        __syncthreads();
        sc[tid] += t;
        __syncthreads();
    }
    int ex = sc[tid] - s;
    gbase[2 * tid] = ex;          gcursor[2 * tid] = ex;
    gbase[2 * tid + 1] = ex + a0; gcursor[2 * tid + 1] = ex + a0;
    if (tid == 255) gbase[512] = sc[255];
}

// ---------------- bin: append packed edges into bucket-contiguous runs ----------------
// pack: src (25 bits) | (dst&127) << 25   (requires n < 2^25)

#define EPB 4096
__global__ __launch_bounds__(256) void bin_kernel(const int* __restrict__ src,
                                                  const int* __restrict__ dst,
                                                  int* __restrict__ gcursor,
                                                  unsigned* __restrict__ binned, int E) {
    __shared__ int hist[512];
    __shared__ int base[512];
    int tid = threadIdx.x;
    int e0 = blockIdx.x * EPB;
    hist[tid] = 0; hist[tid + 256] = 0;
    __syncthreads();
    unsigned pk[16]; int bv[16];
#pragma unroll
    for (int i = 0; i < 16; ++i) {
        int e = e0 + i * 256 + tid;
        if (e < E) {
            int s = src[e], d = dst[e];
            bv[i] = d >> 7;
            pk[i] = (unsigned)s | ((unsigned)(d & 127) << 25);
            atomicAdd(&hist[bv[i]], 1);
        } else bv[i] = -1;
    }
    __syncthreads();
    {
        int c0 = hist[tid];
        base[tid] = c0 ? atomicAdd(&gcursor[tid], c0) : 0;
        hist[tid] = 0;
        int c1 = hist[tid + 256];
        base[tid + 256] = c1 ? atomicAdd(&gcursor[tid + 256], c1) : 0;
        hist[tid + 256] = 0;
    }
    __syncthreads();
#pragma unroll
    for (int i = 0; i < 16; ++i) {
        if (bv[i] >= 0) {
            int off = atomicAdd(&hist[bv[i]], 1);
            binned[base[bv[i]] + off] = pk[i];
        }
    }
}

// ---------------- place: per bucket, derive row_ptr/inv_deg + place col ----------------

__global__ __launch_bounds__(256) void place_kernel(const unsigned* __restrict__ binned,
                                                    const int* __restrict__ gbase,
                                                    int* __restrict__ row_ptr,
                                                    float* __restrict__ inv_deg,
                                                    int* __restrict__ col,
                                                    int n, int E, int NB) {
    __shared__ int cnt[128];
    __shared__ int sc[128];
    __shared__ int cur[128];
    int b = blockIdx.x, tid = threadIdx.x;
    int node0 = b << 7;
    int node1 = node0 + 128; if (node1 > n) node1 = n;
    int start = gbase[b], end = gbase[b + 1];
    if (tid < 128) cnt[tid] = 0;
    __syncthreads();
    for (int i = start + tid; i < end; i += 256)
        atomicAdd(&cnt[binned[i] >> 25], 1);
    __syncthreads();
    if (tid < 128) sc[tid] = cnt[tid];
    __syncthreads();
    for (int off = 1; off < 128; off <<= 1) {
        int t = (tid < 128 && tid >= off) ? sc[tid - off] : 0;
        __syncthreads();
        if (tid < 128) sc[tid] += t;
        __syncthreads();
    }
    if (tid < 128) {
        int nd = node0 + tid;
        if (nd < node1) {
            int c = cnt[tid];
            int base = start + sc[tid] - c;
            row_ptr[nd] = base;
            inv_deg[nd] = 1.0f / (float)((c > 0) ? c : 1);
            cur[tid] = base;
        }
    }
    if (b == NB - 1 && tid == 0) row_ptr[n] = E;
    __syncthreads();
    for (int i = start + tid; i < end; i += 256) {
        unsigned e = binned[i];
        int pos = atomicAdd(&cur[e >> 25], 1);
        col[pos] = (int)(e & 0x01FFFFFFu);
    }
}

// ---------------- mean aggregation (bf16 in/out, f32 accumulate) ----------------
// one wave per node; 4 groups x 16 lanes x 16B; 4 gathers in flight per group.
// nontemporal: gathered rows have no L1 reuse -> bypass L1.

__global__ __launch_bounds__(256) void agg_kernel(
        const short* __restrict__ h, const int* __restrict__ row_ptr,
        const int* __restrict__ col, const float* __restrict__ inv_deg,
        short* __restrict__ out, int n) {
    int w = (blockIdx.x * blockDim.x + threadIdx.x) >> 6;
    int lane = threadIdx.x & 63;
    if (w >= n) return;
    int s = row_ptr[w], e = row_ptr[w + 1];
    int g = lane >> 4, l16 = lane & 15;
    float acc[8];
#pragma unroll
    for (int q = 0; q < 8; ++q) acc[q] = 0.f;
    int p = s + g;
    for (; p + 12 < e; p += 16) {
        int j0 = col[p];
        int j1 = col[p + 4];
        int j2 = col[p + 8];
        int j3 = col[p + 12];
        bf16x8 v0 = __builtin_nontemporal_load((const bf16x8*)(h + (size_t)j0 * D + l16 * 8));
        bf16x8 v1 = __builtin_nontemporal_load((const bf16x8*)(h + (size_t)j1 * D + l16 * 8));
        bf16x8 v2 = __builtin_nontemporal_load((const bf16x8*)(h + (size_t)j2 * D + l16 * 8));
        bf16x8 v3 = __builtin_nontemporal_load((const bf16x8*)(h + (size_t)j3 * D + l16 * 8));
#pragma unroll
        for (int q = 0; q < 8; ++q) acc[q] += b2f(v0[q]);
#pragma unroll
        for (int q = 0; q < 8; ++q) acc[q] += b2f(v1[q]);
#pragma unroll
        for (int q = 0; q < 8; ++q) acc[q] += b2f(v2[q]);
#pragma unroll
        for (int q = 0; q < 8; ++q) acc[q] += b2f(v3[q]);
    }
    for (; p < e; p += 4) {
        int j = col[p];
        bf16x8 v = __builtin_nontemporal_load((const bf16x8*)(h + (size_t)j * D + l16 * 8));
#pragma unroll
        for (int q = 0; q < 8; ++q) acc[q] += b2f(v[q]);
    }
#pragma unroll
    for (int q = 0; q < 8; ++q) {
        acc[q] += __shfl_xor(acc[q], 16, 64);
        acc[q] += __shfl_xor(acc[q], 32, 64);
    }
    if (g == 0) {
        float sc = inv_deg[w];
        bf16x8 o;
#pragma unroll
        for (int q = 0; q < 8; ++q) o[q] = f2b(acc[q] * sc);
        *(bf16x8*)(out + (size_t)w * D + l16 * 8) = o;
    }
}

// ---------------- fused dual GEMM, bf16 MFMA ----------------
// A staged in LDS (36.9 KB -> 4 blocks/CU); W read as B-frags direct from global
// (32 KB table, L1/L2-resident; pattern numerically validated in R7).

__global__ __launch_bounds__(256) void sage_mm_mfma(
        const short* __restrict__ Aagg, const short* __restrict__ Hin,
        const short* __restrict__ WlT,  const short* __restrict__ WrT,
        const float* __restrict__ bl,   short* __restrict__ out, int M) {
    __shared__ short lA[128 * SA];
    int tid  = threadIdx.x;
    int wave = tid >> 6, lane = tid & 63;
    int row0 = blockIdx.x * 128;
    int mrow = wave * 32;
    int m16  = lane & 15, quad = lane >> 4;

    f32x4 acc[2][8];
#pragma unroll
    for (int i = 0; i < 2; ++i)
#pragma unroll
        for (int j = 0; j < 8; ++j) acc[i][j] = (f32x4){0.f, 0.f, 0.f, 0.f};

#pragma unroll
    for (int half = 0; half < 2; ++half) {
        const short* A = half ? Hin : Aagg;
        const short* W = half ? WrT : WlT;
        // stage A tile (128 x 128 bf16), 16B/lane
#pragma unroll
        for (int it = 0; it < 8; ++it) {
            int idx = it * 256 + tid;
            int r = idx >> 4, c8 = (idx & 15) << 3;
            bf16x8 va = {0, 0, 0, 0, 0, 0, 0, 0};
            int gr = row0 + r;
            if (gr < M) va = *(const bf16x8*)(A + (size_t)gr * D + c8);
            *(bf16x8*)(&lA[r * SA + c8]) = va;
        }
        __syncthreads();
#pragma unroll
        for (int ks = 0; ks < 4; ++ks) {
            int kb = ks * 32 + quad * 8;
            bf16x8 a0 = *(const bf16x8*)(&lA[(mrow +      m16) * SA + kb]);
            bf16x8 a1 = *(const bf16x8*)(&lA[(mrow + 16 + m16) * SA + kb]);
#pragma unroll
            for (int nt = 0; nt < 8; ++nt) {
                bf16x8 b = *(const bf16x8*)(W + (nt * 16 + m16) * D + kb);
                acc[0][nt] = __builtin_amdgcn_mfma_f32_16x16x32_bf16(a0, b, acc[0][nt], 0, 0, 0);
                acc[1][nt] = __builtin_amdgcn_mfma_f32_16x16x32_bf16(a1, b, acc[1][nt], 0, 0, 0);
            }
        }
        __syncthreads();
    }
#pragma unroll
    for (int mt = 0; mt < 2; ++mt) {
#pragma unroll
        for (int r = 0; r < 4; ++r) {
            int grow = row0 + mrow + mt * 16 + quad * 4 + r;
            if (grow < M) {
#pragma unroll
                for (int nt = 0; nt < 8; ++nt) {
                    int gcol = nt * 16 + m16;
                    float v = acc[mt][nt][r] + bl[gcol];
                    out[(size_t)grow * D + gcol] = f2b(fmaxf(v, 0.f));
                }
            }
        }
    }
}

// ---------------- fused global-max-pool + MLP head, one block per graph ----------------

__global__ __launch_bounds__(256) void poolhead_kernel(
        const short* __restrict__ h, const int* __restrict__ batch,
        const float* __restrict__ x,
        const float* __restrict__ W_f1, const float* __restrict__ b_f1,
        const float* __restrict__ W_f2, const float* __restrict__ b_f2,
        const float* __restrict__ W_sm, const float* __restrict__ b_sm,
        const float* __restrict__ W_news, const float* __restrict__ b_news,
        const float* __restrict__ W_cat, const float* __restrict__ b_cat,
        float* __restrict__ out, int n) {
    int g = blockIdx.x;
    int tid = threadIdx.x;
    int f = tid & 127, half = tid >> 7;
    __shared__ float pm[256];
    __shared__ float p[128], t1[256], t2[128], hs[2], nw[2];
    int lo = 0, hi = n;
    while (lo < hi) { int m = (lo + hi) >> 1; if (batch[m] < g) lo = m + 1; else hi = m; }
    int start = lo;
    hi = n;
    while (lo < hi) { int m = (lo + hi) >> 1; if (batch[m] < g + 1) lo = m + 1; else hi = m; }
    int end = lo;
    float m = -3.4e38f;
    for (int i = start + half; i < end; i += 2) m = fmaxf(m, b2f(h[(size_t)i * D + f]));
    pm[tid] = m;
    __syncthreads();
    if (tid < 128) p[tid] = fmaxf(pm[tid], pm[tid + 128]);
    __syncthreads();
    float a1 = b_f1[tid];
    for (int k = 0; k < 128; ++k) a1 += p[k] * W_f1[k * 256 + tid];
    t1[tid] = fmaxf(a1, 0.f);
    __syncthreads();
    if (tid < 128) {
        float a2 = b_f2[tid];
        for (int k = 0; k < 256; ++k) a2 += t1[k] * W_f2[k * 128 + tid];
        t2[tid] = fmaxf(a2, 0.f);
    }
    __syncthreads();
    if (tid < 2) {
        float a3 = b_sm[tid];
        for (int k = 0; k < 128; ++k) a3 += t2[k] * W_sm[k * 2 + tid];
        hs[tid] = fmaxf(a3, 0.f);
        const float* xr = x + (size_t)start * D;
        float a4 = b_news[tid];
        for (int k = 0; k < 128; ++k) a4 += xr[k] * W_news[k * 2 + tid];
        nw[tid] = fmaxf(a4, 0.f);
    }
    __syncthreads();
    if (tid == 0) {
        float o = b_cat[0] + hs[0] * W_cat[0] + hs[1] * W_cat[1]
                           + nw[0] * W_cat[2] + nw[1] * W_cat[3];
        out[g] = 1.0f / (1.0f + __expf(-o));
    }
}

// ---------------- launch ----------------

extern "C" void kernel_launch(void* const* d_in, const int* in_sizes, int n_in,
                              void* d_out, int out_size, void* d_ws, size_t ws_size,
                              hipStream_t stream) {
    const float* x      = (const float*)d_in[0];
    const int*   edge   = (const int*)d_in[1];
    const int*   batch  = (const int*)d_in[2];
    const float* Wl1 = (const float*)d_in[3];
    const float* Wr1 = (const float*)d_in[4];
    const float* bl1 = (const float*)d_in[5];
    const float* Wl2 = (const float*)d_in[6];
    const float* Wr2 = (const float*)d_in[7];
    const float* bl2 = (const float*)d_in[8];
    const float* Wl3 = (const float*)d_in[9];
    const float* Wr3 = (const float*)d_in[10];
    const float* bl3 = (const float*)d_in[11];
    const float* W_f1 = (const float*)d_in[12];
    const float* b_f1 = (const float*)d_in[13];
    const float* W_f2 = (const float*)d_in[14];
    const float* b_f2 = (const float*)d_in[15];
    const float* W_sm = (const float*)d_in[16];
    const float* b_sm = (const float*)d_in[17];
    const float* W_news = (const float*)d_in[18];
    const float* b_news = (const float*)d_in[19];
    const float* W_cat = (const float*)d_in[20];
    const float* b_cat = (const float*)d_in[21];
    float* out = (float*)d_out;

    const int E = in_sizes[1] / 2;
    const int n = in_sizes[2];
    const int B = out_size;

    const int* src = edge;
    const int* dst = edge + E;

    char* ws = (char*)d_ws;
    size_t off = 0;
    auto carve = [&](size_t bytes) {
        void* pt = ws + off;
        off = (off + bytes + 255) & ~(size_t)255;
        return pt;
    };
    int*      row_ptr = (int*)carve((size_t)(n + 1) * 4);
    float*    inv_deg = (float*)carve((size_t)n * 4);
    int*      col     = (int*)carve((size_t)E * 4);
    int*      bcnt    = (int*)carve((size_t)512 * 4);
    int*      gbase   = (int*)carve((size_t)513 * 4);
    int*      gcursor = (int*)carve((size_t)512 * 4);
    unsigned* binned  = (unsigned*)carve((size_t)E * 4);
    short*    xb      = (short*)carve((size_t)n * D * 2);
    short*    aggb    = (short*)carve((size_t)n * D * 2);
    short*    hA      = (short*)carve((size_t)n * D * 2);
    short*    hB      = (short*)carve((size_t)n * D * 2);
    short* Wt[6];
    for (int i = 0; i < 6; ++i) Wt[i] = (short*)carve((size_t)D * D * 2);
    (void)ws_size;

    // --- prep: conv_x + conv_w + bucket histogram ---
    hipMemsetAsync(bcnt, 0, 512 * 4, stream);
    PrepArgs pa;
    pa.x = x; pa.xb = xb; pa.total4 = n * D / 4;
    pa.xb_blocks = (pa.total4 + 255) / 256;
    pa.w[0] = Wl1; pa.w[1] = Wr1; pa.w[2] = Wl2; pa.w[3] = Wr2; pa.w[4] = Wl3; pa.w[5] = Wr3;
    for (int i = 0; i < 6; ++i) pa.wo[i] = Wt[i];
    pa.w_blocks = (6 * D * D) / 1024;
    pa.dst = dst; pa.bcnt = bcnt; pa.E = E;
    int h_blocks = (E + 4095) / 4096;
    prep_kernel<<<pa.xb_blocks + pa.w_blocks + h_blocks, 256, 0, stream>>>(pa);

    // --- CSR ---
    int NB = (n + 127) / 128;   // <=512 buckets
    scan512_kernel<<<1, 256, 0, stream>>>(bcnt, gbase, gcursor);
    bin_kernel<<<(E + EPB - 1) / EPB, 256, 0, stream>>>(src, dst, gcursor, binned, E);
    place_kernel<<<NB, 256, 0, stream>>>(binned, gbase, row_ptr, inv_deg, col, n, E, NB);

    int agg_blocks = (n * 64 + 255) / 256;
    int mm_blocks  = (n + 127) / 128;

    agg_kernel<<<agg_blocks, 256, 0, stream>>>(xb, row_ptr, col, inv_deg, aggb, n);
    sage_mm_mfma<<<mm_blocks, 256, 0, stream>>>(aggb, xb, Wt[0], Wt[1], bl1, hA, n);
    agg_kernel<<<agg_blocks, 256, 0, stream>>>(hA, row_ptr, col, inv_deg, aggb, n);
    sage_mm_mfma<<<mm_blocks, 256, 0, stream>>>(aggb, hA, Wt[2], Wt[3], bl2, hB, n);
    agg_kernel<<<agg_blocks, 256, 0, stream>>>(hB, row_ptr, col, inv_deg, aggb, n);
    sage_mm_mfma<<<mm_blocks, 256, 0, stream>>>(aggb, hB, Wt[4], Wt[5], bl3, hA, n);

    poolhead_kernel<<<B, 256, 0, stream>>>(hA, batch, x,
                                           W_f1, b_f1, W_f2, b_f2, W_sm, b_sm,
                                           W_news, b_news, W_cat, b_cat, out, n);
}

// Round 10
// 311.522 us; speedup vs baseline: 1.2854x; 1.2854x over previous
//
#include <hip/hip_runtime.h>
#include <hip/hip_bf16.h>
#include <math.h>

#define D 128
#define SA 144   // LDS row stride (bf16): 72 dwords % 32 = 8 -> conflict-free b128 reads

typedef __attribute__((ext_vector_type(8))) short bf16x8;
typedef __attribute__((ext_vector_type(4))) float f32x4;

static __device__ __forceinline__ short f2b(float f) {
    unsigned u = __builtin_bit_cast(unsigned, f);
    unsigned r = (u + 0x7FFFu + ((u >> 16) & 1u)) >> 16;
    return (short)r;
}
static __device__ __forceinline__ float b2f(short b) {
    unsigned u = ((unsigned)(unsigned short)b) << 16;
    return __builtin_bit_cast(float, u);
}

// ---------------- prep: conv_x + conv_w + bucket histogram, one launch ----------------

struct PrepArgs {
    const float* x; short* xb; int total4; int xb_blocks;
    const float* w[6]; short* wo[6]; int w_blocks;
    const int* dst; int* bcnt; int E;
};

__global__ __launch_bounds__(256) void prep_kernel(PrepArgs a) {
    int bid = blockIdx.x, tid = threadIdx.x;
    if (bid < a.xb_blocks) {
        int idx = bid * 256 + tid;
        if (idx < a.total4) {
            float4 v = ((const float4*)a.x)[idx];
            short4 o;
            o.x = f2b(v.x); o.y = f2b(v.y); o.z = f2b(v.z); o.w = f2b(v.w);
            ((short4*)a.xb)[idx] = o;
        }
        return;
    }
    if (bid < a.xb_blocks + a.w_blocks) {
        int idx4 = (bid - a.xb_blocks) * 256 + tid;
        int base = idx4 * 4;
        int m = base >> 14;
        int i = base & 16383;
        const float* W = a.w[m];
        short* O = a.wo[m];
        int k = i >> 7, nn = i & 127;
        float4 v = *(const float4*)(W + k * D + nn);
        O[(nn + 0) * D + k] = f2b(v.x);
        O[(nn + 1) * D + k] = f2b(v.y);
        O[(nn + 2) * D + k] = f2b(v.z);
        O[(nn + 3) * D + k] = f2b(v.w);
        return;
    }
    __shared__ int hist[512];
    hist[tid] = 0; hist[tid + 256] = 0;
    __syncthreads();
    int e0 = (bid - a.xb_blocks - a.w_blocks) * 4096;
#pragma unroll
    for (int i = 0; i < 16; ++i) {
        int e = e0 + i * 256 + tid;
        if (e < a.E) atomicAdd(&hist[a.dst[e] >> 7], 1);
    }
    __syncthreads();
    int c = hist[tid];       if (c) atomicAdd(&a.bcnt[tid], c);
    c = hist[tid + 256];     if (c) atomicAdd(&a.bcnt[tid + 256], c);
}

// ---------------- scan of 512 bucket counts (one block) ----------------

__global__ __launch_bounds__(256) void scan512_kernel(const int* __restrict__ bcnt,
                                                      int* __restrict__ gbase,
                                                      int* __restrict__ gcursor) {
    __shared__ int sc[256];
    int tid = threadIdx.x;
    int a0 = bcnt[2 * tid], a1 = bcnt[2 * tid + 1];
    int s = a0 + a1;
    sc[tid] = s;
    __syncthreads();
    for (int off = 1; off < 256; off <<= 1) {
        int t = (tid >= off) ? sc[tid - off] : 0;
        __syncthreads();
        sc[tid] += t;
        __syncthreads();
    }
    int ex = sc[tid] - s;
    gbase[2 * tid] = ex;          gcursor[2 * tid] = ex;
    gbase[2 * tid + 1] = ex + a0; gcursor[2 * tid + 1] = ex + a0;
    if (tid == 255) gbase[512] = sc[255];
}

// ---------------- bin: append packed edges into bucket-contiguous runs ----------------
// pack: src (25 bits) | (dst&127) << 25   (requires n < 2^25)

#define EPB 4096
__global__ __launch_bounds__(256) void bin_kernel(const int* __restrict__ src,
                                                  const int* __restrict__ dst,
                                                  int* __restrict__ gcursor,
                                                  unsigned* __restrict__ binned, int E) {
    __shared__ int hist[512];
    __shared__ int base[512];
    int tid = threadIdx.x;
    int e0 = blockIdx.x * EPB;
    hist[tid] = 0; hist[tid + 256] = 0;
    __syncthreads();
    unsigned pk[16]; int bv[16];
#pragma unroll
    for (int i = 0; i < 16; ++i) {
        int e = e0 + i * 256 + tid;
        if (e < E) {
            int s = src[e], d = dst[e];
            bv[i] = d >> 7;
            pk[i] = (unsigned)s | ((unsigned)(d & 127) << 25);
            atomicAdd(&hist[bv[i]], 1);
        } else bv[i] = -1;
    }
    __syncthreads();
    {
        int c0 = hist[tid];
        base[tid] = c0 ? atomicAdd(&gcursor[tid], c0) : 0;
        hist[tid] = 0;
        int c1 = hist[tid + 256];
        base[tid + 256] = c1 ? atomicAdd(&gcursor[tid + 256], c1) : 0;
        hist[tid + 256] = 0;
    }
    __syncthreads();
#pragma unroll
    for (int i = 0; i < 16; ++i) {
        if (bv[i] >= 0) {
            int off = atomicAdd(&hist[bv[i]], 1);
            binned[base[bv[i]] + off] = pk[i];
        }
    }
}

// ---------------- place: per bucket, derive row_ptr/inv_deg + place col ----------------

__global__ __launch_bounds__(256) void place_kernel(const unsigned* __restrict__ binned,
                                                    const int* __restrict__ gbase,
                                                    int* __restrict__ row_ptr,
                                                    float* __restrict__ inv_deg,
                                                    int* __restrict__ col,
                                                    int n, int E, int NB) {
    __shared__ int cnt[128];
    __shared__ int sc[128];
    __shared__ int cur[128];
    int b = blockIdx.x, tid = threadIdx.x;
    int node0 = b << 7;
    int node1 = node0 + 128; if (node1 > n) node1 = n;
    int start = gbase[b], end = gbase[b + 1];
    if (tid < 128) cnt[tid] = 0;
    __syncthreads();
    for (int i = start + tid; i < end; i += 256)
        atomicAdd(&cnt[binned[i] >> 25], 1);
    __syncthreads();
    if (tid < 128) sc[tid] = cnt[tid];
    __syncthreads();
    for (int off = 1; off < 128; off <<= 1) {
        int t = (tid < 128 && tid >= off) ? sc[tid - off] : 0;
        __syncthreads();
        if (tid < 128) sc[tid] += t;
        __syncthreads();
    }
    if (tid < 128) {
        int nd = node0 + tid;
        if (nd < node1) {
            int c = cnt[tid];
            int base = start + sc[tid] - c;
            row_ptr[nd] = base;
            inv_deg[nd] = 1.0f / (float)((c > 0) ? c : 1);
            cur[tid] = base;
        }
    }
    if (b == NB - 1 && tid == 0) row_ptr[n] = E;
    __syncthreads();
    for (int i = start + tid; i < end; i += 256) {
        unsigned e = binned[i];
        int pos = atomicAdd(&cur[e >> 25], 1);
        col[pos] = (int)(e & 0x01FFFFFFu);
    }
}

// ---------------- mean aggregation (bf16 in/out, f32 accumulate) ----------------
// one wave per node; 4 groups x 16 lanes x 16B; 4 gathers in flight per group.
// Plain loads: gather table must stay L2/L3-resident (nontemporal caused HBM
// refetch, R9: FETCH_SIZE 83.5 MB, agg 48us).

__global__ __launch_bounds__(256) void agg_kernel(
        const short* __restrict__ h, const int* __restrict__ row_ptr,
        const int* __restrict__ col, const float* __restrict__ inv_deg,
        short* __restrict__ out, int n) {
    int w = (blockIdx.x * blockDim.x + threadIdx.x) >> 6;
    int lane = threadIdx.x & 63;
    if (w >= n) return;
    int s = row_ptr[w], e = row_ptr[w + 1];
    int g = lane >> 4, l16 = lane & 15;
    float acc[8];
#pragma unroll
    for (int q = 0; q < 8; ++q) acc[q] = 0.f;
    int p = s + g;
    for (; p + 12 < e; p += 16) {
        int j0 = col[p];
        int j1 = col[p + 4];
        int j2 = col[p + 8];
        int j3 = col[p + 12];
        bf16x8 v0 = *(const bf16x8*)(h + (size_t)j0 * D + l16 * 8);
        bf16x8 v1 = *(const bf16x8*)(h + (size_t)j1 * D + l16 * 8);
        bf16x8 v2 = *(const bf16x8*)(h + (size_t)j2 * D + l16 * 8);
        bf16x8 v3 = *(const bf16x8*)(h + (size_t)j3 * D + l16 * 8);
#pragma unroll
        for (int q = 0; q < 8; ++q) acc[q] += b2f(v0[q]);
#pragma unroll
        for (int q = 0; q < 8; ++q) acc[q] += b2f(v1[q]);
#pragma unroll
        for (int q = 0; q < 8; ++q) acc[q] += b2f(v2[q]);
#pragma unroll
        for (int q = 0; q < 8; ++q) acc[q] += b2f(v3[q]);
    }
    for (; p < e; p += 4) {
        int j = col[p];
        bf16x8 v = *(const bf16x8*)(h + (size_t)j * D + l16 * 8);
#pragma unroll
        for (int q = 0; q < 8; ++q) acc[q] += b2f(v[q]);
    }
#pragma unroll
    for (int q = 0; q < 8; ++q) {
        acc[q] += __shfl_xor(acc[q], 16, 64);
        acc[q] += __shfl_xor(acc[q], 32, 64);
    }
    if (g == 0) {
        float sc = inv_deg[w];
        bf16x8 o;
#pragma unroll
        for (int q = 0; q < 8; ++q) o[q] = f2b(acc[q] * sc);
        *(bf16x8*)(out + (size_t)w * D + l16 * 8) = o;
    }
}

// ---------------- fused dual GEMM, bf16 MFMA (R5/R8 verified version) ----------------
// Both A and W staged in LDS: W-from-global in the MFMA loop serializes on
// vmcnt (R7/R9 evidence, ~+20us/layer). 72KB LDS -> 2 blocks/CU is fine here.

__global__ __launch_bounds__(256) void sage_mm_mfma(
        const short* __restrict__ Aagg, const short* __restrict__ Hin,
        const short* __restrict__ WlT,  const short* __restrict__ WrT,
        const float* __restrict__ bl,   short* __restrict__ out, int M) {
    __shared__ short lA[128 * SA];
    __shared__ short lW[128 * SA];
    int tid  = threadIdx.x;
    int wave = tid >> 6, lane = tid & 63;
    int row0 = blockIdx.x * 128;
    int mrow = wave * 32;
    int m16  = lane & 15, quad = lane >> 4;

    f32x4 acc[2][8];
#pragma unroll
    for (int i = 0; i < 2; ++i)
#pragma unroll
        for (int j = 0; j < 8; ++j) acc[i][j] = (f32x4){0.f, 0.f, 0.f, 0.f};

#pragma unroll
    for (int half = 0; half < 2; ++half) {
        const short* A = half ? Hin : Aagg;
        const short* W = half ? WrT : WlT;
#pragma unroll
        for (int it = 0; it < 8; ++it) {
            int idx = it * 256 + tid;
            int r = idx >> 4, c8 = (idx & 15) << 3;
            bf16x8 va = {0, 0, 0, 0, 0, 0, 0, 0};
            int gr = row0 + r;
            if (gr < M) va = *(const bf16x8*)(A + (size_t)gr * D + c8);
            *(bf16x8*)(&lA[r * SA + c8]) = va;
            bf16x8 vw = *(const bf16x8*)(W + r * D + c8);
            *(bf16x8*)(&lW[r * SA + c8]) = vw;
        }
        __syncthreads();
#pragma unroll
        for (int ks = 0; ks < 4; ++ks) {
            int kb = ks * 32 + quad * 8;
            bf16x8 a0 = *(const bf16x8*)(&lA[(mrow +      m16) * SA + kb]);
            bf16x8 a1 = *(const bf16x8*)(&lA[(mrow + 16 + m16) * SA + kb]);
#pragma unroll
            for (int nt = 0; nt < 8; ++nt) {
                bf16x8 b = *(const bf16x8*)(&lW[(nt * 16 + m16) * SA + kb]);
                acc[0][nt] = __builtin_amdgcn_mfma_f32_16x16x32_bf16(a0, b, acc[0][nt], 0, 0, 0);
                acc[1][nt] = __builtin_amdgcn_mfma_f32_16x16x32_bf16(a1, b, acc[1][nt], 0, 0, 0);
            }
        }
        __syncthreads();
    }
#pragma unroll
    for (int mt = 0; mt < 2; ++mt) {
#pragma unroll
        for (int r = 0; r < 4; ++r) {
            int grow = row0 + mrow + mt * 16 + quad * 4 + r;
            if (grow < M) {
#pragma unroll
                for (int nt = 0; nt < 8; ++nt) {
                    int gcol = nt * 16 + m16;
                    float v = acc[mt][nt][r] + bl[gcol];
                    out[(size_t)grow * D + gcol] = f2b(fmaxf(v, 0.f));
                }
            }
        }
    }
}

// ---------------- fused global-max-pool + MLP head, one block per graph ----------------

__global__ __launch_bounds__(256) void poolhead_kernel(
        const short* __restrict__ h, const int* __restrict__ batch,
        const float* __restrict__ x,
        const float* __restrict__ W_f1, const float* __restrict__ b_f1,
        const float* __restrict__ W_f2, const float* __restrict__ b_f2,
        const float* __restrict__ W_sm, const float* __restrict__ b_sm,
        const float* __restrict__ W_news, const float* __restrict__ b_news,
        const float* __restrict__ W_cat, const float* __restrict__ b_cat,
        float* __restrict__ out, int n) {
    int g = blockIdx.x;
    int tid = threadIdx.x;
    int f = tid & 127, half = tid >> 7;
    __shared__ float pm[256];
    __shared__ float p[128], t1[256], t2[128], hs[2], nw[2];
    int lo = 0, hi = n;
    while (lo < hi) { int m = (lo + hi) >> 1; if (batch[m] < g) lo = m + 1; else hi = m; }
    int start = lo;
    hi = n;
    while (lo < hi) { int m = (lo + hi) >> 1; if (batch[m] < g + 1) lo = m + 1; else hi = m; }
    int end = lo;
    float m = -3.4e38f;
    for (int i = start + half; i < end; i += 2) m = fmaxf(m, b2f(h[(size_t)i * D + f]));
    pm[tid] = m;
    __syncthreads();
    if (tid < 128) p[tid] = fmaxf(pm[tid], pm[tid + 128]);
    __syncthreads();
    float a1 = b_f1[tid];
    for (int k = 0; k < 128; ++k) a1 += p[k] * W_f1[k * 256 + tid];
    t1[tid] = fmaxf(a1, 0.f);
    __syncthreads();
    if (tid < 128) {
        float a2 = b_f2[tid];
        for (int k = 0; k < 256; ++k) a2 += t1[k] * W_f2[k * 128 + tid];
        t2[tid] = fmaxf(a2, 0.f);
    }
    __syncthreads();
    if (tid < 2) {
        float a3 = b_sm[tid];
        for (int k = 0; k < 128; ++k) a3 += t2[k] * W_sm[k * 2 + tid];
        hs[tid] = fmaxf(a3, 0.f);
        const float* xr = x + (size_t)start * D;
        float a4 = b_news[tid];
        for (int k = 0; k < 128; ++k) a4 += xr[k] * W_news[k * 2 + tid];
        nw[tid] = fmaxf(a4, 0.f);
    }
    __syncthreads();
    if (tid == 0) {
        float o = b_cat[0] + hs[0] * W_cat[0] + hs[1] * W_cat[1]
                           + nw[0] * W_cat[2] + nw[1] * W_cat[3];
        out[g] = 1.0f / (1.0f + __expf(-o));
    }
}

// ---------------- launch ----------------

extern "C" void kernel_launch(void* const* d_in, const int* in_sizes, int n_in,
                              void* d_out, int out_size, void* d_ws, size_t ws_size,
                              hipStream_t stream) {
    const float* x      = (const float*)d_in[0];
    const int*   edge   = (const int*)d_in[1];
    const int*   batch  = (const int*)d_in[2];
    const float* Wl1 = (const float*)d_in[3];
    const float* Wr1 = (const float*)d_in[4];
    const float* bl1 = (const float*)d_in[5];
    const float* Wl2 = (const float*)d_in[6];
    const float* Wr2 = (const float*)d_in[7];
    const float* bl2 = (const float*)d_in[8];
    const float* Wl3 = (const float*)d_in[9];
    const float* Wr3 = (const float*)d_in[10];
    const float* bl3 = (const float*)d_in[11];
    const float* W_f1 = (const float*)d_in[12];
    const float* b_f1 = (const float*)d_in[13];
    const float* W_f2 = (const float*)d_in[14];
    const float* b_f2 = (const float*)d_in[15];
    const float* W_sm = (const float*)d_in[16];
    const float* b_sm = (const float*)d_in[17];
    const float* W_news = (const float*)d_in[18];
    const float* b_news = (const float*)d_in[19];
    const float* W_cat = (const float*)d_in[20];
    const float* b_cat = (const float*)d_in[21];
    float* out = (float*)d_out;

    const int E = in_sizes[1] / 2;
    const int n = in_sizes[2];
    const int B = out_size;

    const int* src = edge;
    const int* dst = edge + E;

    char* ws = (char*)d_ws;
    size_t off = 0;
    auto carve = [&](size_t bytes) {
        void* pt = ws + off;
        off = (off + bytes + 255) & ~(size_t)255;
        return pt;
    };
    int*      row_ptr = (int*)carve((size_t)(n + 1) * 4);
    float*    inv_deg = (float*)carve((size_t)n * 4);
    int*      col     = (int*)carve((size_t)E * 4);
    int*      bcnt    = (int*)carve((size_t)512 * 4);
    int*      gbase   = (int*)carve((size_t)513 * 4);
    int*      gcursor = (int*)carve((size_t)512 * 4);
    unsigned* binned  = (unsigned*)carve((size_t)E * 4);
    short*    xb      = (short*)carve((size_t)n * D * 2);
    short*    aggb    = (short*)carve((size_t)n * D * 2);
    short*    hA      = (short*)carve((size_t)n * D * 2);
    short*    hB      = (short*)carve((size_t)n * D * 2);
    short* Wt[6];
    for (int i = 0; i < 6; ++i) Wt[i] = (short*)carve((size_t)D * D * 2);
    (void)ws_size;

    // --- prep: conv_x + conv_w + bucket histogram ---
    hipMemsetAsync(bcnt, 0, 512 * 4, stream);
    PrepArgs pa;
    pa.x = x; pa.xb = xb; pa.total4 = n * D / 4;
    pa.xb_blocks = (pa.total4 + 255) / 256;
    pa.w[0] = Wl1; pa.w[1] = Wr1; pa.w[2] = Wl2; pa.w[3] = Wr2; pa.w[4] = Wl3; pa.w[5] = Wr3;
    for (int i = 0; i < 6; ++i) pa.wo[i] = Wt[i];
    pa.w_blocks = (6 * D * D) / 1024;
    pa.dst = dst; pa.bcnt = bcnt; pa.E = E;
    int h_blocks = (E + 4095) / 4096;
    prep_kernel<<<pa.xb_blocks + pa.w_blocks + h_blocks, 256, 0, stream>>>(pa);

    // --- CSR ---
    int NB = (n + 127) / 128;   // <=512 buckets
    scan512_kernel<<<1, 256, 0, stream>>>(bcnt, gbase, gcursor);
    bin_kernel<<<(E + EPB - 1) / EPB, 256, 0, stream>>>(src, dst, gcursor, binned, E);
    place_kernel<<<NB, 256, 0, stream>>>(binned, gbase, row_ptr, inv_deg, col, n, E, NB);

    int agg_blocks = (n * 64 + 255) / 256;
    int mm_blocks  = (n + 127) / 128;

    agg_kernel<<<agg_blocks, 256, 0, stream>>>(xb, row_ptr, col, inv_deg, aggb, n);
    sage_mm_mfma<<<mm_blocks, 256, 0, stream>>>(aggb, xb, Wt[0], Wt[1], bl1, hA, n);
    agg_kernel<<<agg_blocks, 256, 0, stream>>>(hA, row_ptr, col, inv_deg, aggb, n);
    sage_mm_mfma<<<mm_blocks, 256, 0, stream>>>(aggb, hA, Wt[2], Wt[3], bl2, hB, n);
    agg_kernel<<<agg_blocks, 256, 0, stream>>>(hB, row_ptr, col, inv_deg, aggb, n);
    sage_mm_mfma<<<mm_blocks, 256, 0, stream>>>(aggb, hB, Wt[4], Wt[5], bl3, hA, n);

    poolhead_kernel<<<B, 256, 0, stream>>>(hA, batch, x,
                                           W_f1, b_f1, W_f2, b_f2, W_sm, b_sm,
                                           W_news, b_news, W_cat, b_cat, out, n);
}